// Round 8
// baseline (374.199 us; speedup 1.0000x reference)
//
#include <hip/hip_runtime.h>
#include <hip/hip_bf16.h>
#include <math.h>

#define B_  8
#define N_  1024
#define H_  512
#define NH_ 8
#define HD_ 64

typedef __attribute__((ext_vector_type(8))) short short8;
typedef __attribute__((ext_vector_type(4))) short short4_t;
typedef __attribute__((ext_vector_type(4))) float floatx4;

#define GPTR(p) ((const __attribute__((address_space(1))) void*)(p))
#define LPTR(p) ((__attribute__((address_space(3))) void*)(p))

// ds_read_b64_tr_b16: lane l elem j <- lds[region + j*16 + (l&15)] (bf16 elems)
#define TRB16(dst, addr, IMM) \
    asm volatile("ds_read_b64_tr_b16 %0, %1 offset:" IMM \
                 : "=v"(dst) : "v"(addr) : "memory")

#define EXP2(x) exp2f(x)
#define LOG2E 1.44269504088896f

static __device__ __forceinline__ unsigned short f2bf(float f) {
    __hip_bfloat16 h = __float2bfloat16(f);
    unsigned short u;
    __builtin_memcpy(&u, &h, 2);
    return u;
}

// ---------------------------------------------------------------------------
// fp32 -> bf16 for x and the 4 weights into one blob [xb | Wq | Wk | Wv | Wo]
// ---------------------------------------------------------------------------
__global__ __launch_bounds__(256) void cvt_all(
    const float* __restrict__ x,  const float* __restrict__ wq,
    const float* __restrict__ wk, const float* __restrict__ wv,
    const float* __restrict__ wo, unsigned short* __restrict__ dst)
{
    const int n4 = (4194304 + 4 * 262144) / 4;
    int i = blockIdx.x * blockDim.x + threadIdx.x;
    const int stride = gridDim.x * blockDim.x;
    for (; i < n4; i += stride) {
        const int e = i * 4;
        const float* src;
        if (e < 4194304) {
            src = x + e;
        } else {
            const int rel = e - 4194304;
            const int w = rel >> 18;
            const int off = rel & 262143;
            src = (w == 0 ? wq : w == 1 ? wk : w == 2 ? wv : wo) + off;
        }
        const float4 v = *(const float4*)src;
        ushort4 r;
        r.x = f2bf(v.x); r.y = f2bf(v.y); r.z = f2bf(v.z); r.w = f2bf(v.w);
        *(ushort4*)(dst + e) = r;
    }
}

// ---------------------------------------------------------------------------
// binsT[b][k][q] = mask[b][k] ? 255 : clip(int(dist[b][q][k]*10),0,49)
// ---------------------------------------------------------------------------
__global__ __launch_bounds__(256) void binsT_kernel(
    const float* __restrict__ dist, const int* __restrict__ mask,
    unsigned char* __restrict__ binsT)
{
    const int kt = blockIdx.x, qt = blockIdx.y, b = blockIdx.z;
    const int q0 = qt * 64, k0 = kt * 64;
    __shared__ unsigned char Lb[64][80];

    const int t = threadIdx.x;
    {
        const int qr = t >> 2, kc = (t & 3) * 16;
        const float* src = dist + ((size_t)(b * N_) + q0 + qr) * N_ + k0 + kc;
        unsigned w[4];
        #pragma unroll
        for (int i = 0; i < 4; ++i) {
            const float4 v = *(const float4*)(src + 4 * i);
            int b0 = (int)(v.x * 10.f); b0 = b0 < 0 ? 0 : (b0 > 49 ? 49 : b0);
            int b1 = (int)(v.y * 10.f); b1 = b1 < 0 ? 0 : (b1 > 49 ? 49 : b1);
            int b2 = (int)(v.z * 10.f); b2 = b2 < 0 ? 0 : (b2 > 49 ? 49 : b2);
            int b3 = (int)(v.w * 10.f); b3 = b3 < 0 ? 0 : (b3 > 49 ? 49 : b3);
            w[i] = (unsigned)b0 | ((unsigned)b1 << 8) | ((unsigned)b2 << 16) | ((unsigned)b3 << 24);
        }
        uint4 u; u.x = w[0]; u.y = w[1]; u.z = w[2]; u.w = w[3];
        *(uint4*)&Lb[qr][kc] = u;
    }
    __syncthreads();
    {
        const int kr = t >> 2, qc = (t & 3) * 16;
        uint4 u;
        if (mask[b * N_ + k0 + kr]) {
            u.x = u.y = u.z = u.w = 0xFFFFFFFFu;
        } else {
            unsigned w[4];
            #pragma unroll
            for (int i = 0; i < 4; ++i) {
                w[i] = (unsigned)Lb[qc + 4 * i + 0][kr]
                     | ((unsigned)Lb[qc + 4 * i + 1][kr] << 8)
                     | ((unsigned)Lb[qc + 4 * i + 2][kr] << 16)
                     | ((unsigned)Lb[qc + 4 * i + 3][kr] << 24);
            }
            u.x = w[0]; u.y = w[1]; u.z = w[2]; u.w = w[3];
        }
        *(uint4*)(binsT + ((size_t)(b * N_) + k0 + kr) * N_ + q0 + qc) = u;
    }
}

// ---------------------------------------------------------------------------
// MFMA GEMM (m97 structure), unchanged.
// ---------------------------------------------------------------------------
template <int BF16OUT>
static __device__ __forceinline__ void gemm_core(
    const unsigned short* __restrict__ A, const unsigned short* __restrict__ W,
    const float* __restrict__ bias, void* __restrict__ C,
    int Ncols, int K, float scale, int row0, int col0)
{
    __shared__ unsigned short As[128 * 32];
    __shared__ unsigned short Bs[128 * 32];

    const int t    = threadIdx.x;
    const int lane = t & 63;
    const int wave = t >> 6;
    const int wr   = wave >> 1;
    const int wc   = wave & 1;
    const int l15  = lane & 15;
    const int lhi  = lane >> 4;

    const int srow = wave * 32 + (lane >> 2);
    const int sk   = (lane & 3) * 8;
    const unsigned short* gA = A + (size_t)(row0 + srow) * K + sk;
    const unsigned short* gB = W + (size_t)(col0 + srow) * K + sk;

    floatx4 acc[4][4];
    #pragma unroll
    for (int m = 0; m < 4; ++m)
        #pragma unroll
        for (int n = 0; n < 4; ++n) acc[m][n] = (floatx4)0.f;

    for (int k0 = 0; k0 < K; k0 += 32) {
        __syncthreads();
        #pragma unroll
        for (int i = 0; i < 2; ++i) {
            __builtin_amdgcn_global_load_lds(GPTR(gA + (size_t)(i * 16) * K + k0),
                                             LPTR(&As[(wave * 32 + i * 16) * 32]), 16, 0, 0);
            __builtin_amdgcn_global_load_lds(GPTR(gB + (size_t)(i * 16) * K + k0),
                                             LPTR(&Bs[(wave * 32 + i * 16) * 32]), 16, 0, 0);
        }
        __syncthreads();

        short8 af[4], bf[4];
        #pragma unroll
        for (int m = 0; m < 4; ++m)
            af[m] = *(const short8*)&As[(wr * 64 + m * 16 + l15) * 32 + lhi * 8];
        #pragma unroll
        for (int n = 0; n < 4; ++n)
            bf[n] = *(const short8*)&Bs[(wc * 64 + n * 16 + l15) * 32 + lhi * 8];
        #pragma unroll
        for (int m = 0; m < 4; ++m)
            #pragma unroll
            for (int n = 0; n < 4; ++n)
                acc[m][n] = __builtin_amdgcn_mfma_f32_16x16x32_bf16(af[m], bf[n], acc[m][n], 0, 0, 0);
    }

    #pragma unroll
    for (int n = 0; n < 4; ++n) {
        const int col = col0 + wc * 64 + n * 16 + l15;
        const float bvv = bias[col];
        #pragma unroll
        for (int m = 0; m < 4; ++m) {
            #pragma unroll
            for (int r = 0; r < 4; ++r) {
                const int row = row0 + wr * 64 + m * 16 + lhi * 4 + r;
                const float v = (acc[m][n][r] + bvv) * scale;
                if (BF16OUT)
                    ((unsigned short*)C)[(size_t)row * Ncols + col] = f2bf(v);
                else
                    ((float*)C)[(size_t)row * Ncols + col] = v;
            }
        }
    }
}

__global__ __launch_bounds__(256) void gemm_qkv(
    const unsigned short* __restrict__ xb,
    const unsigned short* __restrict__ Wq, const unsigned short* __restrict__ Wk,
    const unsigned short* __restrict__ Wv,
    const float* __restrict__ bq, const float* __restrict__ bk,
    const float* __restrict__ bv,
    unsigned short* __restrict__ Qb, unsigned short* __restrict__ Kb,
    unsigned short* __restrict__ Vb)
{
    const int z = blockIdx.z;
    const unsigned short* W = z == 0 ? Wq : (z == 1 ? Wk : Wv);
    const float* bias       = z == 0 ? bq : (z == 1 ? bk : bv);
    unsigned short* C       = z == 0 ? Qb : (z == 1 ? Kb : Vb);
    const float scale       = z == 0 ? (0.125f * LOG2E) : 1.0f;
    gemm_core<1>(xb, W, bias, C, H_, H_, scale, blockIdx.y * 128, blockIdx.x * 128);
}

__global__ __launch_bounds__(256) void gemm_out(
    const unsigned short* __restrict__ Ab, const unsigned short* __restrict__ Wo,
    const float* __restrict__ bo, float* __restrict__ out)
{
    gemm_core<0>(Ab, Wo, bo, out, H_, H_, 1.0f, blockIdx.y * 128, blockIdx.x * 128);
}

// ---------------------------------------------------------------------------
// MFMA flash attention (R6 structure) with ablation variants:
//  V=0 full | V=1 no-softmax | V=2 no-bias | V=3 no-PV | V=4 stage-once
// Probe variants (V>0) produce garbage into a scratch target; the real V0
// dispatch runs first so d_out stays exact & deterministic.
// ---------------------------------------------------------------------------
template <int V>
static __device__ __forceinline__ void attn_core(
    const unsigned short* __restrict__ Qg, const unsigned short* __restrict__ Kg,
    const unsigned short* __restrict__ Vg, const unsigned char* __restrict__ binsT,
    const float* __restrict__ demb, const float* __restrict__ abias,
    unsigned short* __restrict__ O)
{
    const int qt = blockIdx.x;
    const int h  = blockIdx.y;
    const int b  = blockIdx.z;
    const int q0 = qt * 64;
    const int t  = threadIdx.x;
    const int lane = t & 63;
    const int wave = t >> 6;
    const int l15 = lane & 15;
    const int lhi = lane >> 4;

    __shared__ unsigned short Ks[64 * 64];
    __shared__ unsigned short Vs[64 * 64];
    __shared__ unsigned short QPs[64 * 64];
    __shared__ unsigned char  BsT[64 * 80];

    float dbl = -1.442695e9f;
    if (lane < 50) dbl = (demb[lane * NH_ + h] + abias[h]) * LOG2E;

    {
        const int qr = t >> 2;
        const int d0 = (t & 3) * 16;
        const unsigned short* src = Qg + ((size_t)(b * N_ + q0 + qr)) * H_ + h * HD_ + d0;
        #pragma unroll
        for (int cc = 0; cc < 2; ++cc) {
            const uint4 v = *(const uint4*)(src + 8 * cc);
            const int idx = (qr * 64 + d0 + 8 * cc) ^ ((qr & 7) << 3);
            *(uint4*)&QPs[idx] = v;
        }
    }
    __syncthreads();

    short8 aq[2];
    {
        const int qrow = (wave << 4) + l15;
        #pragma unroll
        for (int ck = 0; ck < 2; ++ck) {
            const int kb = lhi * 8 + 32 * ck;
            const int idx = (qrow * 64 + kb) ^ ((qrow & 7) << 3);
            aq[ck] = *(const short8*)&QPs[idx];
        }
    }

    unsigned short* const Pw = &QPs[wave << 10];
    const unsigned trlane = (unsigned)(lhi << 8) + (unsigned)(l15 << 3);
    const unsigned paddr = (unsigned)(size_t)LPTR(Pw) + trlane;
    const unsigned vaddr = (unsigned)(size_t)LPTR(&Vs[0]) + trlane;

    const int vcc   = t & 1;
    const int krlow = (t >> 1) & 3;
    const int vd16  = (t >> 3) & 3;
    const int krh0  = t >> 5;

    float m[4], lsum[4];
    floatx4 o4[4];
    #pragma unroll
    for (int r = 0; r < 4; ++r) { m[r] = -INFINITY; lsum[r] = 0.f; }
    #pragma unroll
    for (int nd = 0; nd < 4; ++nd) o4[nd] = (floatx4)0.f;

    for (int k0 = 0; k0 < N_; k0 += 64) {
        __syncthreads();
        if (V != 4 || k0 == 0) {
            const int kr = t >> 2;
            const int d0 = (t & 3) * 16;
            const unsigned short* ksrc = Kg + ((size_t)(b * N_ + k0 + kr)) * H_ + h * HD_ + d0;
            #pragma unroll
            for (int cc = 0; cc < 2; ++cc) {
                const uint4 kv = *(const uint4*)(ksrc + 8 * cc);
                const int idx = (kr * 64 + d0 + 8 * cc) ^ ((kr & 7) << 3);
                *(uint4*)&Ks[idx] = kv;
            }
            #pragma unroll
            for (int it = 0; it < 2; ++it) {
                const int krhi = krh0 + 8 * it;
                const int vkr  = krhi * 4 + krlow;
                const uint4 vv = *(const uint4*)(Vg + ((size_t)(b * N_ + k0 + vkr)) * H_
                                                 + h * HD_ + vd16 * 16 + vcc * 8);
                *(uint4*)&Vs[vd16 * 1024 + krhi * 64 + krlow * 16 + vcc * 8] = vv;
            }
            if (V != 2) {
                const int qc = (t & 3) * 16;
                *(uint4*)&BsT[kr * 80 + qc] =
                    *(const uint4*)(binsT + ((size_t)(b * N_) + k0 + kr) * N_ + q0 + qc);
            }
        }
        __syncthreads();

        // ---- S = (Q * 0.125*log2e) K^T ----
        floatx4 s4[4];
        __builtin_amdgcn_s_setprio(1);
        #pragma unroll
        for (int kn = 0; kn < 4; ++kn) {
            const int kcol = kn * 16 + l15;
            floatx4 acc = (floatx4)0.f;
            #pragma unroll
            for (int ck = 0; ck < 2; ++ck) {
                const int kb = lhi * 8 + 32 * ck;
                const int idx = (kcol * 64 + kb) ^ ((kcol & 7) << 3);
                const short8 bk = *(const short8*)&Ks[idx];
                acc = __builtin_amdgcn_mfma_f32_16x16x32_bf16(aq[ck], bk, acc, 0, 0, 0);
            }
            s4[kn] = acc;
        }
        __builtin_amdgcn_s_setprio(0);

        // ---- + distance bias ----
        if (V != 2) {
            #pragma unroll
            for (int kn = 0; kn < 4; ++kn) {
                const int k = kn * 16 + l15;
                const unsigned bb = *(const unsigned*)&BsT[k * 80 + (wave << 4) + (lhi << 2)];
                s4[kn][0] += __shfl(dbl, (int)(bb & 255u), 64);
                s4[kn][1] += __shfl(dbl, (int)((bb >> 8) & 255u), 64);
                s4[kn][2] += __shfl(dbl, (int)((bb >> 16) & 255u), 64);
                s4[kn][3] += __shfl(dbl, (int)(bb >> 24), 64);
            }
        }

        // ---- online softmax (exp2 domain) ----
        if (V != 1) {
            #pragma unroll
            for (int r = 0; r < 4; ++r) {
                float tm = fmaxf(fmaxf(s4[0][r], s4[1][r]), fmaxf(s4[2][r], s4[3][r]));
                tm = fmaxf(tm, __shfl_xor(tm, 1, 64));
                tm = fmaxf(tm, __shfl_xor(tm, 2, 64));
                tm = fmaxf(tm, __shfl_xor(tm, 4, 64));
                tm = fmaxf(tm, __shfl_xor(tm, 8, 64));
                const float mnew = fmaxf(m[r], tm);
                float ts = 0.f;
                #pragma unroll
                for (int kn = 0; kn < 4; ++kn) {
                    const float pexp = EXP2(s4[kn][r] - mnew);
                    s4[kn][r] = pexp;
                    ts += pexp;
                }
                ts += __shfl_xor(ts, 1, 64);
                ts += __shfl_xor(ts, 2, 64);
                ts += __shfl_xor(ts, 4, 64);
                ts += __shfl_xor(ts, 8, 64);
                const float alpha = EXP2(m[r] - mnew);
                lsum[r] = lsum[r] * alpha + ts;
                m[r] = mnew;
                #pragma unroll
                for (int nd = 0; nd < 4; ++nd) o4[nd][r] *= alpha;
            }
        }

        if (V != 3) {
            // ---- P_T -> LDS (per-wave region) ----
            #pragma unroll
            for (int kn = 0; kn < 4; ++kn) {
                short4_t pk;
                pk[0] = (short)f2bf(s4[kn][0]);
                pk[1] = (short)f2bf(s4[kn][1]);
                pk[2] = (short)f2bf(s4[kn][2]);
                pk[3] = (short)f2bf(s4[kn][3]);
                *(short4_t*)&Pw[kn * 256 + (l15 >> 2) * 64 + (l15 & 3) * 16 + lhi * 4] = pk;
            }
            asm volatile("s_waitcnt lgkmcnt(0)" ::: "memory");
            __builtin_amdgcn_sched_barrier(0);

            // ---- PV via tr-reads ----
            short4_t pa0l, pa0h, pa1l, pa1h;
            short4_t v0l[4], v0h[4], v1l[4], v1h[4];
            TRB16(pa0l, paddr, "0");    TRB16(pa0h, paddr, "128");
            TRB16(pa1l, paddr, "1024"); TRB16(pa1h, paddr, "1152");
            TRB16(v0l[0], vaddr, "0");    TRB16(v0h[0], vaddr, "128");
            TRB16(v0l[1], vaddr, "2048"); TRB16(v0h[1], vaddr, "2176");
            TRB16(v0l[2], vaddr, "4096"); TRB16(v0h[2], vaddr, "4224");
            TRB16(v0l[3], vaddr, "6144"); TRB16(v0h[3], vaddr, "6272");
            TRB16(v1l[0], vaddr, "1024"); TRB16(v1h[0], vaddr, "1152");
            TRB16(v1l[1], vaddr, "3072"); TRB16(v1h[1], vaddr, "3200");
            TRB16(v1l[2], vaddr, "5120"); TRB16(v1h[2], vaddr, "5248");
            TRB16(v1l[3], vaddr, "7168"); TRB16(v1h[3], vaddr, "7296");
            asm volatile("s_waitcnt lgkmcnt(0)" ::: "memory");
            __builtin_amdgcn_sched_barrier(0);

            const short8 ap0 = __builtin_shufflevector(pa0l, pa0h, 0, 1, 2, 3, 4, 5, 6, 7);
            const short8 ap1 = __builtin_shufflevector(pa1l, pa1h, 0, 1, 2, 3, 4, 5, 6, 7);
            __builtin_amdgcn_s_setprio(1);
            #pragma unroll
            for (int nd = 0; nd < 4; ++nd) {
                const short8 bv0 = __builtin_shufflevector(v0l[nd], v0h[nd], 0, 1, 2, 3, 4, 5, 6, 7);
                o4[nd] = __builtin_amdgcn_mfma_f32_16x16x32_bf16(ap0, bv0, o4[nd], 0, 0, 0);
                const short8 bv1 = __builtin_shufflevector(v1l[nd], v1h[nd], 0, 1, 2, 3, 4, 5, 6, 7);
                o4[nd] = __builtin_amdgcn_mfma_f32_16x16x32_bf16(ap1, bv1, o4[nd], 0, 0, 0);
            }
            __builtin_amdgcn_s_setprio(0);
        } else {
            // consume s4 so nothing upstream is DCE'd (rule #17)
            #pragma unroll
            for (int nd = 0; nd < 4; ++nd)
                #pragma unroll
                for (int r = 0; r < 4; ++r) o4[nd][r] += s4[nd][r];
        }
    }

    #pragma unroll
    for (int nd = 0; nd < 4; ++nd) {
        const int d = nd * 16 + l15;
        #pragma unroll
        for (int r = 0; r < 4; ++r) {
            const int q = q0 + (wave << 4) + lhi * 4 + r;
            const float ivr = (V == 1) ? 1.f : 1.f / lsum[r];
            O[((size_t)(b * N_ + q)) * H_ + h * HD_ + d] = f2bf(o4[nd][r] * ivr);
        }
    }
}

__global__ __launch_bounds__(256) void attn_mfma(
    const unsigned short* Qg, const unsigned short* Kg, const unsigned short* Vg,
    const unsigned char* binsT, const float* demb, const float* abias,
    unsigned short* O)
{ attn_core<0>(Qg, Kg, Vg, binsT, demb, abias, O); }

__global__ __launch_bounds__(256) void attn_nosm(
    const unsigned short* Qg, const unsigned short* Kg, const unsigned short* Vg,
    const unsigned char* binsT, const float* demb, const float* abias,
    unsigned short* O)
{ attn_core<1>(Qg, Kg, Vg, binsT, demb, abias, O); }

__global__ __launch_bounds__(256) void attn_nobias(
    const unsigned short* Qg, const unsigned short* Kg, const unsigned short* Vg,
    const unsigned char* binsT, const float* demb, const float* abias,
    unsigned short* O)
{ attn_core<2>(Qg, Kg, Vg, binsT, demb, abias, O); }

__global__ __launch_bounds__(256) void attn_nopv(
    const unsigned short* Qg, const unsigned short* Kg, const unsigned short* Vg,
    const unsigned char* binsT, const float* demb, const float* abias,
    unsigned short* O)
{ attn_core<3>(Qg, Kg, Vg, binsT, demb, abias, O); }

__global__ __launch_bounds__(256) void attn_nostage(
    const unsigned short* Qg, const unsigned short* Kg, const unsigned short* Vg,
    const unsigned char* binsT, const float* demb, const float* abias,
    unsigned short* O)
{ attn_core<4>(Qg, Kg, Vg, binsT, demb, abias, O); }

// ---------------------------------------------------------------------------
extern "C" void kernel_launch(void* const* d_in, const int* in_sizes, int n_in,
                              void* d_out, int out_size, void* d_ws, size_t ws_size,
                              hipStream_t stream)
{
    const float* x    = (const float*)d_in[0];
    const float* dist = (const float*)d_in[1];
    const int*   mask = (const int*)d_in[2];
    const float* Wq   = (const float*)d_in[3];
    const float* bq   = (const float*)d_in[4];
    const float* Wk   = (const float*)d_in[5];
    const float* bk   = (const float*)d_in[6];
    const float* Wv   = (const float*)d_in[7];
    const float* bv   = (const float*)d_in[8];
    const float* Wo   = (const float*)d_in[9];
    const float* bo   = (const float*)d_in[10];
    const float* demb = (const float*)d_in[11];
    const float* ab   = (const float*)d_in[12];
    float* out = (float*)d_out;

    const size_t mat = (size_t)B_ * N_ * H_;         // 4,194,304
    const size_t wsz = (size_t)H_ * H_;              //   262,144

    unsigned short* blob = (unsigned short*)d_ws;
    unsigned short* xb  = blob;
    unsigned short* Wqb = blob + mat;
    unsigned short* Wkb = Wqb + wsz;
    unsigned short* Wvb = Wkb + wsz;
    unsigned short* Wob = Wvb + wsz;
    unsigned short* Qb  = Wob + wsz;
    unsigned short* Kb  = Qb + mat;
    unsigned short* Vb  = Kb + mat;
    unsigned short* Ab  = Vb + mat;
    unsigned char*  binsb = (unsigned char*)(Ab + mat);

    const dim3 blk(256);

    hipLaunchKernelGGL(cvt_all, dim3(1024), blk, 0, stream, x, Wq, Wk, Wv, Wo, blob);
    hipLaunchKernelGGL(binsT_kernel, dim3(N_ / 64, N_ / 64, B_), blk, 0, stream,
                       dist, mask, binsb);

    const dim3 qgrid(H_ / 128, (B_ * N_) / 128, 3);
    hipLaunchKernelGGL(gemm_qkv, qgrid, blk, 0, stream,
                       xb, Wqb, Wkb, Wvb, bq, bk, bv, Qb, Kb, Vb);

    const dim3 agrid(N_ / 64, NH_, B_);
    // real attention first (pristine inputs) -> Ab
    hipLaunchKernelGGL(attn_mfma, agrid, blk, 0, stream,
                       Qb, Kb, Vb, binsb, demb, ab, Ab);

    // ---- ablation probes: outputs (garbage) go over the spent bins buffer;
    //      they never feed d_out. rocprof per-dispatch rows = phase costs. ----
    unsigned short* probeO = (unsigned short*)binsb;   // 8 MB, exactly B*N*H bf16
    hipLaunchKernelGGL(attn_nosm,    agrid, blk, 0, stream, Qb, Kb, Vb, binsb, demb, ab, probeO);
    hipLaunchKernelGGL(attn_nobias,  agrid, blk, 0, stream, Qb, Kb, Vb, binsb, demb, ab, probeO);
    hipLaunchKernelGGL(attn_nopv,    agrid, blk, 0, stream, Qb, Kb, Vb, binsb, demb, ab, probeO);
    hipLaunchKernelGGL(attn_nostage, agrid, blk, 0, stream, Qb, Kb, Vb, binsb, demb, ab, probeO);

    const dim3 ogrid(H_ / 128, (B_ * N_) / 128, 1);
    hipLaunchKernelGGL(gemm_out, ogrid, blk, 0, stream, Ab, Wob, bo, out);
}

// Round 9
// 132.114 us; speedup vs baseline: 2.8324x; 2.8324x over previous
//
#include <hip/hip_runtime.h>
#include <hip/hip_bf16.h>
#include <math.h>

#define B_  8
#define N_  1024
#define H_  512
#define NH_ 8
#define HD_ 64

typedef __attribute__((ext_vector_type(8))) short short8;
typedef __attribute__((ext_vector_type(4))) short short4_t;
typedef __attribute__((ext_vector_type(4))) float floatx4;

#define GPTR(p) ((const __attribute__((address_space(1))) void*)(p))
#define LPTR(p) ((__attribute__((address_space(3))) void*)(p))

// ds_read_b64_tr_b16: lane l elem j <- lds[region + j*16 + (l&15)] (bf16 elems)
#define TRB16(dst, addr, IMM) \
    asm volatile("ds_read_b64_tr_b16 %0, %1 offset:" IMM \
                 : "=v"(dst) : "v"(addr) : "memory")

#define EXP2(x) exp2f(x)
#define LOG2E 1.44269504088896f

static __device__ __forceinline__ unsigned short f2bf(float f) {
    __hip_bfloat16 h = __float2bfloat16(f);
    unsigned short u;
    __builtin_memcpy(&u, &h, 2);
    return u;
}
static __device__ __forceinline__ float bf2f(unsigned short u) {
    unsigned v = ((unsigned)u) << 16;
    float f;
    __builtin_memcpy(&f, &v, 4);
    return f;
}

// ---------------------------------------------------------------------------
// fp32 -> bf16 for x and the 4 weights into one blob [xb | Wq | Wk | Wv | Wo]
// ---------------------------------------------------------------------------
__global__ __launch_bounds__(256) void cvt_all(
    const float* __restrict__ x,  const float* __restrict__ wq,
    const float* __restrict__ wk, const float* __restrict__ wv,
    const float* __restrict__ wo, unsigned short* __restrict__ dst)
{
    const int n4 = (4194304 + 4 * 262144) / 4;
    int i = blockIdx.x * blockDim.x + threadIdx.x;
    const int stride = gridDim.x * blockDim.x;
    for (; i < n4; i += stride) {
        const int e = i * 4;
        const float* src;
        if (e < 4194304) {
            src = x + e;
        } else {
            const int rel = e - 4194304;
            const int w = rel >> 18;
            const int off = rel & 262143;
            src = (w == 0 ? wq : w == 1 ? wk : w == 2 ? wv : wo) + off;
        }
        const float4 v = *(const float4*)src;
        ushort4 r;
        r.x = f2bf(v.x); r.y = f2bf(v.y); r.z = f2bf(v.z); r.w = f2bf(v.w);
        *(ushort4*)(dst + e) = r;
    }
}

// ---------------------------------------------------------------------------
// binsT[b][k][q] = mask[b][k] ? 255 : clip(int(dist[b][q][k]*10),0,49)
// ---------------------------------------------------------------------------
__global__ __launch_bounds__(256) void binsT_kernel(
    const float* __restrict__ dist, const int* __restrict__ mask,
    unsigned char* __restrict__ binsT)
{
    const int kt = blockIdx.x, qt = blockIdx.y, b = blockIdx.z;
    const int q0 = qt * 64, k0 = kt * 64;
    __shared__ unsigned char Lb[64][80];

    const int t = threadIdx.x;
    {
        const int qr = t >> 2, kc = (t & 3) * 16;
        const float* src = dist + ((size_t)(b * N_) + q0 + qr) * N_ + k0 + kc;
        unsigned w[4];
        #pragma unroll
        for (int i = 0; i < 4; ++i) {
            const float4 v = *(const float4*)(src + 4 * i);
            int b0 = (int)(v.x * 10.f); b0 = b0 < 0 ? 0 : (b0 > 49 ? 49 : b0);
            int b1 = (int)(v.y * 10.f); b1 = b1 < 0 ? 0 : (b1 > 49 ? 49 : b1);
            int b2 = (int)(v.z * 10.f); b2 = b2 < 0 ? 0 : (b2 > 49 ? 49 : b2);
            int b3 = (int)(v.w * 10.f); b3 = b3 < 0 ? 0 : (b3 > 49 ? 49 : b3);
            w[i] = (unsigned)b0 | ((unsigned)b1 << 8) | ((unsigned)b2 << 16) | ((unsigned)b3 << 24);
        }
        uint4 u; u.x = w[0]; u.y = w[1]; u.z = w[2]; u.w = w[3];
        *(uint4*)&Lb[qr][kc] = u;
    }
    __syncthreads();
    {
        const int kr = t >> 2, qc = (t & 3) * 16;
        uint4 u;
        if (mask[b * N_ + k0 + kr]) {
            u.x = u.y = u.z = u.w = 0xFFFFFFFFu;
        } else {
            unsigned w[4];
            #pragma unroll
            for (int i = 0; i < 4; ++i) {
                w[i] = (unsigned)Lb[qc + 4 * i + 0][kr]
                     | ((unsigned)Lb[qc + 4 * i + 1][kr] << 8)
                     | ((unsigned)Lb[qc + 4 * i + 2][kr] << 16)
                     | ((unsigned)Lb[qc + 4 * i + 3][kr] << 24);
            }
            u.x = w[0]; u.y = w[1]; u.z = w[2]; u.w = w[3];
        }
        *(uint4*)(binsT + ((size_t)(b * N_) + k0 + kr) * N_ + q0 + qc) = u;
    }
}

// ---------------------------------------------------------------------------
// MFMA GEMM (m97 structure), unchanged.
// ---------------------------------------------------------------------------
template <int BF16OUT>
static __device__ __forceinline__ void gemm_core(
    const unsigned short* __restrict__ A, const unsigned short* __restrict__ W,
    const float* __restrict__ bias, void* __restrict__ C,
    int Ncols, int K, float scale, int row0, int col0)
{
    __shared__ unsigned short As[128 * 32];
    __shared__ unsigned short Bs[128 * 32];

    const int t    = threadIdx.x;
    const int lane = t & 63;
    const int wave = t >> 6;
    const int wr   = wave >> 1;
    const int wc   = wave & 1;
    const int l15  = lane & 15;
    const int lhi  = lane >> 4;

    const int srow = wave * 32 + (lane >> 2);
    const int sk   = (lane & 3) * 8;
    const unsigned short* gA = A + (size_t)(row0 + srow) * K + sk;
    const unsigned short* gB = W + (size_t)(col0 + srow) * K + sk;

    floatx4 acc[4][4];
    #pragma unroll
    for (int m = 0; m < 4; ++m)
        #pragma unroll
        for (int n = 0; n < 4; ++n) acc[m][n] = (floatx4)0.f;

    for (int k0 = 0; k0 < K; k0 += 32) {
        __syncthreads();
        #pragma unroll
        for (int i = 0; i < 2; ++i) {
            __builtin_amdgcn_global_load_lds(GPTR(gA + (size_t)(i * 16) * K + k0),
                                             LPTR(&As[(wave * 32 + i * 16) * 32]), 16, 0, 0);
            __builtin_amdgcn_global_load_lds(GPTR(gB + (size_t)(i * 16) * K + k0),
                                             LPTR(&Bs[(wave * 32 + i * 16) * 32]), 16, 0, 0);
        }
        __syncthreads();

        short8 af[4], bf[4];
        #pragma unroll
        for (int m = 0; m < 4; ++m)
            af[m] = *(const short8*)&As[(wr * 64 + m * 16 + l15) * 32 + lhi * 8];
        #pragma unroll
        for (int n = 0; n < 4; ++n)
            bf[n] = *(const short8*)&Bs[(wc * 64 + n * 16 + l15) * 32 + lhi * 8];
        #pragma unroll
        for (int m = 0; m < 4; ++m)
            #pragma unroll
            for (int n = 0; n < 4; ++n)
                acc[m][n] = __builtin_amdgcn_mfma_f32_16x16x32_bf16(af[m], bf[n], acc[m][n], 0, 0, 0);
    }

    #pragma unroll
    for (int n = 0; n < 4; ++n) {
        const int col = col0 + wc * 64 + n * 16 + l15;
        const float bvv = bias[col];
        #pragma unroll
        for (int m = 0; m < 4; ++m) {
            #pragma unroll
            for (int r = 0; r < 4; ++r) {
                const int row = row0 + wr * 64 + m * 16 + lhi * 4 + r;
                const float v = (acc[m][n][r] + bvv) * scale;
                if (BF16OUT)
                    ((unsigned short*)C)[(size_t)row * Ncols + col] = f2bf(v);
                else
                    ((float*)C)[(size_t)row * Ncols + col] = v;
            }
        }
    }
}

__global__ __launch_bounds__(256) void gemm_qkv(
    const unsigned short* __restrict__ xb,
    const unsigned short* __restrict__ Wq, const unsigned short* __restrict__ Wk,
    const unsigned short* __restrict__ Wv,
    const float* __restrict__ bq, const float* __restrict__ bk,
    const float* __restrict__ bv,
    unsigned short* __restrict__ Qb, unsigned short* __restrict__ Kb,
    unsigned short* __restrict__ Vb)
{
    const int z = blockIdx.z;
    const unsigned short* W = z == 0 ? Wq : (z == 1 ? Wk : Wv);
    const float* bias       = z == 0 ? bq : (z == 1 ? bk : bv);
    unsigned short* C       = z == 0 ? Qb : (z == 1 ? Kb : Vb);
    const float scale       = z == 0 ? (0.125f * LOG2E) : 1.0f;
    gemm_core<1>(xb, W, bias, C, H_, H_, scale, blockIdx.y * 128, blockIdx.x * 128);
}

__global__ __launch_bounds__(256) void gemm_out(
    const unsigned short* __restrict__ Ab, const unsigned short* __restrict__ Wo,
    const float* __restrict__ bo, float* __restrict__ out)
{
    gemm_core<0>(Ab, Wo, bo, out, H_, H_, 1.0f, blockIdx.y * 128, blockIdx.x * 128);
}

// ---------------------------------------------------------------------------
// MFMA flash attention (R6 structure) with key-split (flash-decoding):
// blockIdx.x = qt*2 + ks; split ks handles k in [ks*512, ks*512+512).
// Each split writes a NORMALIZED partial O (bf16) + per-row (m, l) f32;
// attn_combine merges the two splits. 2048 blocks -> 5 resident/CU (LDS cap).
// ---------------------------------------------------------------------------
__global__ __launch_bounds__(256) void attn_mfma(
    const unsigned short* __restrict__ Qg, const unsigned short* __restrict__ Kg,
    const unsigned short* __restrict__ Vg, const unsigned char* __restrict__ binsT,
    const float* __restrict__ demb, const float* __restrict__ abias,
    unsigned short* __restrict__ O0, unsigned short* __restrict__ O1,
    float2* __restrict__ mlbuf)
{
    const int bx = blockIdx.x;
    const int qt = bx >> 1;
    const int ks = bx & 1;
    const int kbase = ks * (N_ / 2);
    const int h  = blockIdx.y;
    const int b  = blockIdx.z;
    const int q0 = qt * 64;
    const int t  = threadIdx.x;
    const int lane = t & 63;
    const int wave = t >> 6;
    const int l15 = lane & 15;
    const int lhi = lane >> 4;

    __shared__ unsigned short Ks[64 * 64];
    __shared__ unsigned short Vs[64 * 64];
    __shared__ unsigned short QPs[64 * 64];
    __shared__ unsigned char  BsT[64 * 80];

    float dbl = -1.442695e9f;
    if (lane < 50) dbl = (demb[lane * NH_ + h] + abias[h]) * LOG2E;

    {
        const int qr = t >> 2;
        const int d0 = (t & 3) * 16;
        const unsigned short* src = Qg + ((size_t)(b * N_ + q0 + qr)) * H_ + h * HD_ + d0;
        #pragma unroll
        for (int cc = 0; cc < 2; ++cc) {
            const uint4 v = *(const uint4*)(src + 8 * cc);
            const int idx = (qr * 64 + d0 + 8 * cc) ^ ((qr & 7) << 3);
            *(uint4*)&QPs[idx] = v;
        }
    }
    __syncthreads();

    short8 aq[2];
    {
        const int qrow = (wave << 4) + l15;
        #pragma unroll
        for (int ck = 0; ck < 2; ++ck) {
            const int kb = lhi * 8 + 32 * ck;
            const int idx = (qrow * 64 + kb) ^ ((qrow & 7) << 3);
            aq[ck] = *(const short8*)&QPs[idx];
        }
    }

    unsigned short* const Pw = &QPs[wave << 10];
    const unsigned trlane = (unsigned)(lhi << 8) + (unsigned)(l15 << 3);
    const unsigned paddr = (unsigned)(size_t)LPTR(Pw) + trlane;
    const unsigned vaddr = (unsigned)(size_t)LPTR(&Vs[0]) + trlane;

    const int vcc   = t & 1;
    const int krlow = (t >> 1) & 3;
    const int vd16  = (t >> 3) & 3;
    const int krh0  = t >> 5;

    float m[4], lsum[4];
    floatx4 o4[4];
    #pragma unroll
    for (int r = 0; r < 4; ++r) { m[r] = -INFINITY; lsum[r] = 0.f; }
    #pragma unroll
    for (int nd = 0; nd < 4; ++nd) o4[nd] = (floatx4)0.f;

    for (int tt = 0; tt < 8; ++tt) {
        const int k0 = kbase + tt * 64;
        __syncthreads();
        {
            const int kr = t >> 2;
            const int d0 = (t & 3) * 16;
            const unsigned short* ksrc = Kg + ((size_t)(b * N_ + k0 + kr)) * H_ + h * HD_ + d0;
            #pragma unroll
            for (int cc = 0; cc < 2; ++cc) {
                const uint4 kv = *(const uint4*)(ksrc + 8 * cc);
                const int idx = (kr * 64 + d0 + 8 * cc) ^ ((kr & 7) << 3);
                *(uint4*)&Ks[idx] = kv;
            }
            #pragma unroll
            for (int it = 0; it < 2; ++it) {
                const int krhi = krh0 + 8 * it;
                const int vkr  = krhi * 4 + krlow;
                const uint4 vv = *(const uint4*)(Vg + ((size_t)(b * N_ + k0 + vkr)) * H_
                                                 + h * HD_ + vd16 * 16 + vcc * 8);
                *(uint4*)&Vs[vd16 * 1024 + krhi * 64 + krlow * 16 + vcc * 8] = vv;
            }
            const int qc = (t & 3) * 16;
            *(uint4*)&BsT[kr * 80 + qc] =
                *(const uint4*)(binsT + ((size_t)(b * N_) + k0 + kr) * N_ + q0 + qc);
        }
        __syncthreads();

        // ---- S = (Q * 0.125*log2e) K^T ----
        floatx4 s4[4];
        __builtin_amdgcn_s_setprio(1);
        #pragma unroll
        for (int kn = 0; kn < 4; ++kn) {
            const int kcol = kn * 16 + l15;
            floatx4 acc = (floatx4)0.f;
            #pragma unroll
            for (int ck = 0; ck < 2; ++ck) {
                const int kb = lhi * 8 + 32 * ck;
                const int idx = (kcol * 64 + kb) ^ ((kcol & 7) << 3);
                const short8 bk = *(const short8*)&Ks[idx];
                acc = __builtin_amdgcn_mfma_f32_16x16x32_bf16(aq[ck], bk, acc, 0, 0, 0);
            }
            s4[kn] = acc;
        }
        __builtin_amdgcn_s_setprio(0);

        // ---- + distance bias via lane-table shuffle (mask folded) ----
        #pragma unroll
        for (int kn = 0; kn < 4; ++kn) {
            const int k = kn * 16 + l15;
            const unsigned bb = *(const unsigned*)&BsT[k * 80 + (wave << 4) + (lhi << 2)];
            s4[kn][0] += __shfl(dbl, (int)(bb & 255u), 64);
            s4[kn][1] += __shfl(dbl, (int)((bb >> 8) & 255u), 64);
            s4[kn][2] += __shfl(dbl, (int)((bb >> 16) & 255u), 64);
            s4[kn][3] += __shfl(dbl, (int)(bb >> 24), 64);
        }

        // ---- online softmax (exp2 domain) ----
        #pragma unroll
        for (int r = 0; r < 4; ++r) {
            float tm = fmaxf(fmaxf(s4[0][r], s4[1][r]), fmaxf(s4[2][r], s4[3][r]));
            tm = fmaxf(tm, __shfl_xor(tm, 1, 64));
            tm = fmaxf(tm, __shfl_xor(tm, 2, 64));
            tm = fmaxf(tm, __shfl_xor(tm, 4, 64));
            tm = fmaxf(tm, __shfl_xor(tm, 8, 64));
            const float mnew = fmaxf(m[r], tm);
            float ts = 0.f;
            #pragma unroll
            for (int kn = 0; kn < 4; ++kn) {
                const float pexp = EXP2(s4[kn][r] - mnew);
                s4[kn][r] = pexp;
                ts += pexp;
            }
            ts += __shfl_xor(ts, 1, 64);
            ts += __shfl_xor(ts, 2, 64);
            ts += __shfl_xor(ts, 4, 64);
            ts += __shfl_xor(ts, 8, 64);
            const float alpha = EXP2(m[r] - mnew);
            lsum[r] = lsum[r] * alpha + ts;
            m[r] = mnew;
            #pragma unroll
            for (int nd = 0; nd < 4; ++nd) o4[nd][r] *= alpha;
        }

        // ---- P_T -> LDS (per-wave region) ----
        #pragma unroll
        for (int kn = 0; kn < 4; ++kn) {
            short4_t pk;
            pk[0] = (short)f2bf(s4[kn][0]);
            pk[1] = (short)f2bf(s4[kn][1]);
            pk[2] = (short)f2bf(s4[kn][2]);
            pk[3] = (short)f2bf(s4[kn][3]);
            *(short4_t*)&Pw[kn * 256 + (l15 >> 2) * 64 + (l15 & 3) * 16 + lhi * 4] = pk;
        }
        asm volatile("s_waitcnt lgkmcnt(0)" ::: "memory");
        __builtin_amdgcn_sched_barrier(0);

        // ---- PV via tr-reads ----
        short4_t pa0l, pa0h, pa1l, pa1h;
        short4_t v0l[4], v0h[4], v1l[4], v1h[4];
        TRB16(pa0l, paddr, "0");    TRB16(pa0h, paddr, "128");
        TRB16(pa1l, paddr, "1024"); TRB16(pa1h, paddr, "1152");
        TRB16(v0l[0], vaddr, "0");    TRB16(v0h[0], vaddr, "128");
        TRB16(v0l[1], vaddr, "2048"); TRB16(v0h[1], vaddr, "2176");
        TRB16(v0l[2], vaddr, "4096"); TRB16(v0h[2], vaddr, "4224");
        TRB16(v0l[3], vaddr, "6144"); TRB16(v0h[3], vaddr, "6272");
        TRB16(v1l[0], vaddr, "1024"); TRB16(v1h[0], vaddr, "1152");
        TRB16(v1l[1], vaddr, "3072"); TRB16(v1h[1], vaddr, "3200");
        TRB16(v1l[2], vaddr, "5120"); TRB16(v1h[2], vaddr, "5248");
        TRB16(v1l[3], vaddr, "7168"); TRB16(v1h[3], vaddr, "7296");
        asm volatile("s_waitcnt lgkmcnt(0)" ::: "memory");
        __builtin_amdgcn_sched_barrier(0);

        const short8 ap0 = __builtin_shufflevector(pa0l, pa0h, 0, 1, 2, 3, 4, 5, 6, 7);
        const short8 ap1 = __builtin_shufflevector(pa1l, pa1h, 0, 1, 2, 3, 4, 5, 6, 7);
        __builtin_amdgcn_s_setprio(1);
        #pragma unroll
        for (int nd = 0; nd < 4; ++nd) {
            const short8 bv0 = __builtin_shufflevector(v0l[nd], v0h[nd], 0, 1, 2, 3, 4, 5, 6, 7);
            o4[nd] = __builtin_amdgcn_mfma_f32_16x16x32_bf16(ap0, bv0, o4[nd], 0, 0, 0);
            const short8 bv1 = __builtin_shufflevector(v1l[nd], v1h[nd], 0, 1, 2, 3, 4, 5, 6, 7);
            o4[nd] = __builtin_amdgcn_mfma_f32_16x16x32_bf16(ap1, bv1, o4[nd], 0, 0, 0);
        }
        __builtin_amdgcn_s_setprio(0);
    }

    // ---- epilogue: normalized partial O + (m, l) per q-row ----
    unsigned short* const O = ks ? O1 : O0;
    float inv[4];
    #pragma unroll
    for (int r = 0; r < 4; ++r) inv[r] = 1.f / lsum[r];
    #pragma unroll
    for (int nd = 0; nd < 4; ++nd) {
        const int d = nd * 16 + l15;
        #pragma unroll
        for (int r = 0; r < 4; ++r) {
            const int q = q0 + (wave << 4) + lhi * 4 + r;
            O[((size_t)(b * N_ + q)) * H_ + h * HD_ + d] = f2bf(o4[nd][r] * inv[r]);
        }
    }
    if (l15 == 0) {
        #pragma unroll
        for (int r = 0; r < 4; ++r) {
            const int q = q0 + (wave << 4) + lhi * 4 + r;
            float2 v; v.x = m[r]; v.y = lsum[r];
            mlbuf[((size_t)(ks * B_ + b) * NH_ + h) * N_ + q] = v;
        }
    }
}

// ---------------------------------------------------------------------------
// Merge the two key-split partials: O = f0*O0 + f1*O1, f_i = l_i*2^(m_i-M)/Z.
// In-place on O0. 8 bf16 per thread, fully coalesced.
// ---------------------------------------------------------------------------
__global__ __launch_bounds__(256) void attn_combine(
    unsigned short* __restrict__ O0, const unsigned short* __restrict__ O1,
    const float2* __restrict__ mlbuf)
{
    const int gid = blockIdx.x * 256 + threadIdx.x;   // 524288 chunks of 8
    const size_t e = (size_t)gid * 8;
    const int b   = gid >> 16;
    const int rem = gid & 65535;
    const int q   = rem >> 6;
    const int h   = (rem & 63) >> 3;

    const float2 a0 = mlbuf[((size_t)b * NH_ + h) * N_ + q];
    const float2 a1 = mlbuf[((size_t)(B_ + b) * NH_ + h) * N_ + q];
    const float M  = fmaxf(a0.x, a1.x);
    const float e0 = exp2f(a0.x - M) * a0.y;
    const float e1 = exp2f(a1.x - M) * a1.y;
    const float zi = 1.f / (e0 + e1);
    const float f0 = e0 * zi, f1 = e1 * zi;

    const short8 v0 = *(const short8*)(O0 + e);
    const short8 v1 = *(const short8*)(O1 + e);
    short8 r;
    #pragma unroll
    for (int j = 0; j < 8; ++j)
        r[j] = (short)f2bf(bf2f((unsigned short)v0[j]) * f0 +
                           bf2f((unsigned short)v1[j]) * f1);
    *(short8*)(O0 + e) = r;
}

// ---------------------------------------------------------------------------
extern "C" void kernel_launch(void* const* d_in, const int* in_sizes, int n_in,
                              void* d_out, int out_size, void* d_ws, size_t ws_size,
                              hipStream_t stream)
{
    const float* x    = (const float*)d_in[0];
    const float* dist = (const float*)d_in[1];
    const int*   mask = (const int*)d_in[2];
    const float* Wq   = (const float*)d_in[3];
    const float* bq   = (const float*)d_in[4];
    const float* Wk   = (const float*)d_in[5];
    const float* bk   = (const float*)d_in[6];
    const float* Wv   = (const float*)d_in[7];
    const float* bv   = (const float*)d_in[8];
    const float* Wo   = (const float*)d_in[9];
    const float* bo   = (const float*)d_in[10];
    const float* demb = (const float*)d_in[11];
    const float* ab   = (const float*)d_in[12];
    float* out = (float*)d_out;

    const size_t mat = (size_t)B_ * N_ * H_;         // 4,194,304
    const size_t wsz = (size_t)H_ * H_;              //   262,144

    unsigned short* blob = (unsigned short*)d_ws;
    unsigned short* xb  = blob;
    unsigned short* Wqb = blob + mat;
    unsigned short* Wkb = Wqb + wsz;
    unsigned short* Wvb = Wkb + wsz;
    unsigned short* Wob = Wvb + wsz;
    unsigned short* Qb  = Wob + wsz;
    unsigned short* Kb  = Qb + mat;
    unsigned short* Vb  = Kb + mat;
    unsigned short* Ab  = Vb + mat;                  // split-0 partial, then merged
    unsigned char*  binsb = (unsigned char*)(Ab + mat);
    unsigned short* Opart1 = (unsigned short*)(binsb + (size_t)B_ * N_ * N_);
    float2*         mlbuf  = (float2*)(Opart1 + mat);

    const dim3 blk(256);

    hipLaunchKernelGGL(cvt_all, dim3(1024), blk, 0, stream, x, Wq, Wk, Wv, Wo, blob);
    hipLaunchKernelGGL(binsT_kernel, dim3(N_ / 64, N_ / 64, B_), blk, 0, stream,
                       dist, mask, binsb);

    const dim3 qgrid(H_ / 128, (B_ * N_) / 128, 3);
    hipLaunchKernelGGL(gemm_qkv, qgrid, blk, 0, stream,
                       xb, Wqb, Wkb, Wvb, bq, bk, bv, Qb, Kb, Vb);

    const dim3 agrid((N_ / 64) * 2, NH_, B_);        // qt x ksplit = 32, 8, 8
    hipLaunchKernelGGL(attn_mfma, agrid, blk, 0, stream,
                       Qb, Kb, Vb, binsb, demb, ab, Ab, Opart1, mlbuf);

    hipLaunchKernelGGL(attn_combine, dim3((int)(mat / 8 / 256)), blk, 0, stream,
                       Ab, Opart1, mlbuf);

    const dim3 ogrid(H_ / 128, (B_ * N_) / 128, 1);
    hipLaunchKernelGGL(gemm_out, ogrid, blk, 0, stream, Ab, Wob, bo, out);
}

// Round 10
// 109.470 us; speedup vs baseline: 3.4183x; 1.2068x over previous
//
#include <hip/hip_runtime.h>
#include <hip/hip_bf16.h>
#include <math.h>

#define B_  8
#define N_  1024
#define H_  512
#define NH_ 8
#define HD_ 64

typedef __attribute__((ext_vector_type(8))) short short8;
typedef __attribute__((ext_vector_type(4))) short short4_t;
typedef __attribute__((ext_vector_type(4))) float floatx4;

#define GPTR(p) ((const __attribute__((address_space(1))) void*)(p))
#define LPTR(p) ((__attribute__((address_space(3))) void*)(p))

// ds_read_b64_tr_b16: lane l elem j <- lds[region + j*16 + (l&15)] (bf16 elems)
#define TRB16(dst, addr, IMM) \
    asm volatile("ds_read_b64_tr_b16 %0, %1 offset:" IMM \
                 : "=v"(dst) : "v"(addr) : "memory")

#define EXP2(x) exp2f(x)
#define LOG2E 1.44269504088896f

static __device__ __forceinline__ unsigned short f2bf(float f) {
    __hip_bfloat16 h = __float2bfloat16(f);
    unsigned short u;
    __builtin_memcpy(&u, &h, 2);
    return u;
}

// ---------------------------------------------------------------------------
// fp32 -> bf16 for x and the 4 weights into one blob [xb | Wq | Wk | Wv | Wo]
// ---------------------------------------------------------------------------
__global__ __launch_bounds__(256) void cvt_all(
    const float* __restrict__ x,  const float* __restrict__ wq,
    const float* __restrict__ wk, const float* __restrict__ wv,
    const float* __restrict__ wo, unsigned short* __restrict__ dst)
{
    const int n4 = (4194304 + 4 * 262144) / 4;
    int i = blockIdx.x * blockDim.x + threadIdx.x;
    const int stride = gridDim.x * blockDim.x;
    for (; i < n4; i += stride) {
        const int e = i * 4;
        const float* src;
        if (e < 4194304) {
            src = x + e;
        } else {
            const int rel = e - 4194304;
            const int w = rel >> 18;
            const int off = rel & 262143;
            src = (w == 0 ? wq : w == 1 ? wk : w == 2 ? wv : wo) + off;
        }
        const float4 v = *(const float4*)src;
        ushort4 r;
        r.x = f2bf(v.x); r.y = f2bf(v.y); r.z = f2bf(v.z); r.w = f2bf(v.w);
        *(ushort4*)(dst + e) = r;
    }
}

// ---------------------------------------------------------------------------
// bins[b][q][k] = mask[b][k] ? 255 : clip(int(dist[b][q][k]*10),0,49)
// Natural (non-transposed) layout; mask folded. 16 elems per thread.
// ---------------------------------------------------------------------------
__global__ __launch_bounds__(256) void bins_kernel(
    const float* __restrict__ dist, const int* __restrict__ mask,
    unsigned char* __restrict__ bins)
{
    const int gid = blockIdx.x * 256 + threadIdx.x;   // 524288 total
    const size_t e = (size_t)gid * 16;
    const int b = gid >> 16;
    const int k = (gid & 63) * 16;
    const float* dsrc = dist + e;
    const int*   msrc = mask + b * N_ + k;

    unsigned w[4];
    #pragma unroll
    for (int i = 0; i < 4; ++i) {
        const float4 v = *(const float4*)(dsrc + 4 * i);
        const int4  mm = *(const int4*)(msrc + 4 * i);
        int b0 = (int)(v.x * 10.f); b0 = b0 < 0 ? 0 : (b0 > 49 ? 49 : b0);
        int b1 = (int)(v.y * 10.f); b1 = b1 < 0 ? 0 : (b1 > 49 ? 49 : b1);
        int b2 = (int)(v.z * 10.f); b2 = b2 < 0 ? 0 : (b2 > 49 ? 49 : b2);
        int b3 = (int)(v.w * 10.f); b3 = b3 < 0 ? 0 : (b3 > 49 ? 49 : b3);
        if (mm.x) b0 = 255;
        if (mm.y) b1 = 255;
        if (mm.z) b2 = 255;
        if (mm.w) b3 = 255;
        w[i] = (unsigned)b0 | ((unsigned)b1 << 8) | ((unsigned)b2 << 16) | ((unsigned)b3 << 24);
    }
    uint4 u; u.x = w[0]; u.y = w[1]; u.z = w[2]; u.w = w[3];
    *(uint4*)(bins + e) = u;
}

// ---------------------------------------------------------------------------
// MFMA GEMM (m97 structure), unchanged.
// ---------------------------------------------------------------------------
template <int BF16OUT>
static __device__ __forceinline__ void gemm_core(
    const unsigned short* __restrict__ A, const unsigned short* __restrict__ W,
    const float* __restrict__ bias, void* __restrict__ C,
    int Ncols, int K, float scale, int row0, int col0)
{
    __shared__ unsigned short As[128 * 32];
    __shared__ unsigned short Bs[128 * 32];

    const int t    = threadIdx.x;
    const int lane = t & 63;
    const int wave = t >> 6;
    const int wr   = wave >> 1;
    const int wc   = wave & 1;
    const int l15  = lane & 15;
    const int lhi  = lane >> 4;

    const int srow = wave * 32 + (lane >> 2);
    const int sk   = (lane & 3) * 8;
    const unsigned short* gA = A + (size_t)(row0 + srow) * K + sk;
    const unsigned short* gB = W + (size_t)(col0 + srow) * K + sk;

    floatx4 acc[4][4];
    #pragma unroll
    for (int m = 0; m < 4; ++m)
        #pragma unroll
        for (int n = 0; n < 4; ++n) acc[m][n] = (floatx4)0.f;

    for (int k0 = 0; k0 < K; k0 += 32) {
        __syncthreads();
        #pragma unroll
        for (int i = 0; i < 2; ++i) {
            __builtin_amdgcn_global_load_lds(GPTR(gA + (size_t)(i * 16) * K + k0),
                                             LPTR(&As[(wave * 32 + i * 16) * 32]), 16, 0, 0);
            __builtin_amdgcn_global_load_lds(GPTR(gB + (size_t)(i * 16) * K + k0),
                                             LPTR(&Bs[(wave * 32 + i * 16) * 32]), 16, 0, 0);
        }
        __syncthreads();

        short8 af[4], bf[4];
        #pragma unroll
        for (int m = 0; m < 4; ++m)
            af[m] = *(const short8*)&As[(wr * 64 + m * 16 + l15) * 32 + lhi * 8];
        #pragma unroll
        for (int n = 0; n < 4; ++n)
            bf[n] = *(const short8*)&Bs[(wc * 64 + n * 16 + l15) * 32 + lhi * 8];
        #pragma unroll
        for (int m = 0; m < 4; ++m)
            #pragma unroll
            for (int n = 0; n < 4; ++n)
                acc[m][n] = __builtin_amdgcn_mfma_f32_16x16x32_bf16(af[m], bf[n], acc[m][n], 0, 0, 0);
    }

    #pragma unroll
    for (int n = 0; n < 4; ++n) {
        const int col = col0 + wc * 64 + n * 16 + l15;
        const float bvv = bias[col];
        #pragma unroll
        for (int m = 0; m < 4; ++m) {
            #pragma unroll
            for (int r = 0; r < 4; ++r) {
                const int row = row0 + wr * 64 + m * 16 + lhi * 4 + r;
                const float v = (acc[m][n][r] + bvv) * scale;
                if (BF16OUT)
                    ((unsigned short*)C)[(size_t)row * Ncols + col] = f2bf(v);
                else
                    ((float*)C)[(size_t)row * Ncols + col] = v;
            }
        }
    }
}

__global__ __launch_bounds__(256) void gemm_qkv(
    const unsigned short* __restrict__ xb,
    const unsigned short* __restrict__ Wq, const unsigned short* __restrict__ Wk,
    const unsigned short* __restrict__ Wv,
    const float* __restrict__ bq, const float* __restrict__ bk,
    const float* __restrict__ bv,
    unsigned short* __restrict__ Qb, unsigned short* __restrict__ Kb,
    unsigned short* __restrict__ Vb)
{
    const int z = blockIdx.z;
    const unsigned short* W = z == 0 ? Wq : (z == 1 ? Wk : Wv);
    const float* bias       = z == 0 ? bq : (z == 1 ? bk : bv);
    unsigned short* C       = z == 0 ? Qb : (z == 1 ? Kb : Vb);
    const float scale       = z == 0 ? (0.125f * LOG2E) : 1.0f;
    gemm_core<1>(xb, W, bias, C, H_, H_, scale, blockIdx.y * 128, blockIdx.x * 128);
}

__global__ __launch_bounds__(256) void gemm_out(
    const unsigned short* __restrict__ Ab, const unsigned short* __restrict__ Wo,
    const float* __restrict__ bo, float* __restrict__ out)
{
    gemm_core<0>(Ab, Wo, bo, out, H_, H_, 1.0f, blockIdx.y * 128, blockIdx.x * 128);
}

// ---------------------------------------------------------------------------
// MFMA flash attention — swapped-QK^T (S^T lane-local softmax) edition.
// Block = 256 thr (4 waves) = one (b, h, 64-q tile). K-tiles of 64.
//  - QK: mfma(K_frag, Q_frag) -> S^T: lane owns q=l15, 16 k-values in regs.
//    Softmax reduce = lane-local + 2 shfl (max) + 2 shfl (sum); alpha
//    broadcast to O-layout rows via 4 shfl. (was 32 shfl)
//  - P kept as P[q][k] in per-wave LDS: 4 b64 writes, A-frag = 2 b128 reads
//    (no P tr-reads, no shufflevector pairs).
//  - K/V staged via global_load_lds (0 ds_writes), pre-swizzled global
//    sources (R7-verified mapping), single-buffered.
//  - bins natural [b][q][k], mask folded (255 -> lane63 -> -1.44e9).
// ---------------------------------------------------------------------------
__global__ __launch_bounds__(256) void attn_mfma(
    const unsigned short* __restrict__ Qg, const unsigned short* __restrict__ Kg,
    const unsigned short* __restrict__ Vg, const unsigned char* __restrict__ bins,
    const float* __restrict__ demb, const float* __restrict__ abias,
    unsigned short* __restrict__ O)
{
    const int qt = blockIdx.x;
    const int h  = blockIdx.y;
    const int b  = blockIdx.z;
    const int q0 = qt * 64;
    const int t  = threadIdx.x;
    const int lane = t & 63;
    const int wave = t >> 6;
    const int l15 = lane & 15;
    const int lhi = lane >> 4;

    __shared__ unsigned short Ks[64 * 64];   // XOR-swizzled rows (linear dest)
    __shared__ unsigned short Vs[64 * 64];   // [d/16][k/4][4][16] subtiled
    __shared__ unsigned short QPs[64 * 64];  // prologue: Q; loop: per-wave P
    __shared__ unsigned char  Bs[64 * 80];   // [q][k] bins tile, stride 80

    // lane-register bias table (log2e domain); lane 63 = masked (-1.44e9)
    float dbl = -1.442695e9f;
    if (lane < 50) dbl = (demb[lane * NH_ + h] + abias[h]) * LOG2E;

    // ---- per-lane staging sources (pre-swizzled for linear LDS dest) ----
    const unsigned short* ksrc[2];
    const unsigned short* vsrc[2];
    #pragma unroll
    for (int i = 0; i < 2; ++i) {
        const int C = wave * 128 + i * 64 + lane;   // LDS 16B-chunk index
        const int kr = C >> 3, c = C & 7;
        ksrc[i] = Kg + ((size_t)(b * N_) + kr) * H_ + h * HD_ + ((c ^ (kr & 7)) * 8);
        const int vd16 = C >> 7, rem = C & 127;
        const int krhi = rem >> 3, r2 = rem & 7;
        const int vkr = krhi * 4 + (r2 >> 1), vc = r2 & 1;
        vsrc[i] = Vg + ((size_t)(b * N_) + vkr) * H_ + h * HD_ + vd16 * 16 + vc * 8;
    }
    const unsigned char* bsrc = bins + ((size_t)(b * N_) + q0 + (t >> 2)) * N_ + (t & 3) * 16;
    const int bidx = (t >> 2) * 80 + (t & 3) * 16;

    // ---- stage Q (pre-scaled by 0.125*log2e), XOR-swizzled ----
    {
        const int qr = t >> 2;
        const int d0 = (t & 3) * 16;
        const unsigned short* src = Qg + ((size_t)(b * N_ + q0 + qr)) * H_ + h * HD_ + d0;
        #pragma unroll
        for (int cc = 0; cc < 2; ++cc) {
            const uint4 v = *(const uint4*)(src + 8 * cc);
            const int idx = (qr * 64 + d0 + 8 * cc) ^ ((qr & 7) << 3);
            *(uint4*)&QPs[idx] = v;
        }
    }
    __syncthreads();

    // Q fragment (B-operand of swapped QK^T; constant over k-tiles)
    short8 aq[2];
    {
        const int qrow = (wave << 4) + l15;
        #pragma unroll
        for (int ck = 0; ck < 2; ++ck) {
            const int kb = lhi * 8 + 32 * ck;
            const int idx = (qrow * 64 + kb) ^ ((qrow & 7) << 3);
            aq[ck] = *(const short8*)&QPs[idx];
        }
    }
    __syncthreads();   // aq reads drained before QPs reused as P

    unsigned short* const Pw = &QPs[wave << 10];   // per-wave 2KB P region
    const unsigned trlane = (unsigned)(lhi << 8) + (unsigned)(l15 << 3);
    const unsigned vaddr = (unsigned)(size_t)LPTR(&Vs[0]) + trlane;

    // per-lane softmax state for q = l15 (replicated across lhi groups)
    float m = -INFINITY, lsum = 0.f;
    floatx4 o4[4];
    #pragma unroll
    for (int nd = 0; nd < 4; ++nd) o4[nd] = (floatx4)0.f;

    for (int k0 = 0; k0 < N_; k0 += 64) {
        __syncthreads();   // previous tile's reads done
        {
            const size_t koff = (size_t)k0;
            #pragma unroll
            for (int i = 0; i < 2; ++i) {
                __builtin_amdgcn_global_load_lds(GPTR(ksrc[i] + koff * H_),
                    LPTR(&Ks[(wave * 128 + i * 64) * 8]), 16, 0, 0);
                __builtin_amdgcn_global_load_lds(GPTR(vsrc[i] + koff * H_),
                    LPTR(&Vs[(wave * 128 + i * 64) * 8]), 16, 0, 0);
            }
            const uint4 brv = *(const uint4*)(bsrc + koff);
            *(uint4*)&Bs[bidx] = brv;
        }
        __syncthreads();   // staging drained (compiler emits vmcnt/lgkm)

        // ---- S^T = K (Q*0.125*log2e)^T : s4[kn][r] = S[q=l15][k=kn*16+lhi*4+r]
        floatx4 s4[4];
        __builtin_amdgcn_s_setprio(1);
        #pragma unroll
        for (int kn = 0; kn < 4; ++kn) {
            const int kcol = kn * 16 + l15;
            floatx4 acc = (floatx4)0.f;
            #pragma unroll
            for (int ck = 0; ck < 2; ++ck) {
                const int kb = lhi * 8 + 32 * ck;
                const int idx = (kcol * 64 + kb) ^ ((kcol & 7) << 3);
                const short8 bk = *(const short8*)&Ks[idx];
                acc = __builtin_amdgcn_mfma_f32_16x16x32_bf16(bk, aq[ck], acc, 0, 0, 0);
            }
            s4[kn] = acc;
        }
        __builtin_amdgcn_s_setprio(0);

        // ---- + distance bias: row q=l15, contiguous k per kn ----
        #pragma unroll
        for (int kn = 0; kn < 4; ++kn) {
            const unsigned bb =
                *(const unsigned*)&Bs[((wave << 4) + l15) * 80 + kn * 16 + (lhi << 2)];
            s4[kn][0] += __shfl(dbl, (int)(bb & 255u), 64);
            s4[kn][1] += __shfl(dbl, (int)((bb >> 8) & 255u), 64);
            s4[kn][2] += __shfl(dbl, (int)((bb >> 16) & 255u), 64);
            s4[kn][3] += __shfl(dbl, (int)(bb >> 24), 64);
        }

        // ---- online softmax: lane-local over 16 regs + 2-level shfl ----
        {
            float mx = s4[0][0];
            #pragma unroll
            for (int kn = 0; kn < 4; ++kn)
                #pragma unroll
                for (int r = 0; r < 4; ++r) mx = fmaxf(mx, s4[kn][r]);
            mx = fmaxf(mx, __shfl_xor(mx, 16, 64));
            mx = fmaxf(mx, __shfl_xor(mx, 32, 64));
            const float mnew = fmaxf(m, mx);
            float ts = 0.f;
            #pragma unroll
            for (int kn = 0; kn < 4; ++kn)
                #pragma unroll
                for (int r = 0; r < 4; ++r) {
                    const float p = EXP2(s4[kn][r] - mnew);
                    s4[kn][r] = p;
                    ts += p;
                }
            ts += __shfl_xor(ts, 16, 64);
            ts += __shfl_xor(ts, 32, 64);
            const float alpha = EXP2(m - mnew);
            lsum = lsum * alpha + ts;
            m = mnew;
            // broadcast alpha to O rows (q = lhi*4+r lives at lane l15=q)
            #pragma unroll
            for (int r = 0; r < 4; ++r) {
                const float ar = __shfl(alpha, lhi * 4 + r, 64);
                #pragma unroll
                for (int nd = 0; nd < 4; ++nd) o4[nd][r] *= ar;
            }
        }

        // ---- P[q=l15][k] -> LDS: 4 b64 writes at contiguous k ----
        #pragma unroll
        for (int kn = 0; kn < 4; ++kn) {
            short4_t pk;
            pk[0] = (short)f2bf(s4[kn][0]);
            pk[1] = (short)f2bf(s4[kn][1]);
            pk[2] = (short)f2bf(s4[kn][2]);
            pk[3] = (short)f2bf(s4[kn][3]);
            const int idx = (l15 * 64 + kn * 16 + (lhi << 2)) ^ ((l15 & 7) << 3);
            *(short4_t*)&Pw[idx] = pk;
        }

        // ---- PV: A = 2 direct b128 P reads; B = 16 V tr-reads ----
        short8 ap[2];
        #pragma unroll
        for (int ck = 0; ck < 2; ++ck) {
            const int idx = (l15 * 64 + ck * 32 + lhi * 8) ^ ((l15 & 7) << 3);
            ap[ck] = *(const short8*)&Pw[idx];
        }
        short4_t v0l[4], v0h[4], v1l[4], v1h[4];
        TRB16(v0l[0], vaddr, "0");    TRB16(v0h[0], vaddr, "128");
        TRB16(v0l[1], vaddr, "2048"); TRB16(v0h[1], vaddr, "2176");
        TRB16(v0l[2], vaddr, "4096"); TRB16(v0h[2], vaddr, "4224");
        TRB16(v0l[3], vaddr, "6144"); TRB16(v0h[3], vaddr, "6272");
        TRB16(v1l[0], vaddr, "1024"); TRB16(v1h[0], vaddr, "1152");
        TRB16(v1l[1], vaddr, "3072"); TRB16(v1h[1], vaddr, "3200");
        TRB16(v1l[2], vaddr, "5120"); TRB16(v1h[2], vaddr, "5248");
        TRB16(v1l[3], vaddr, "7168"); TRB16(v1h[3], vaddr, "7296");
        asm volatile("s_waitcnt lgkmcnt(0)" ::: "memory");
        __builtin_amdgcn_sched_barrier(0);

        __builtin_amdgcn_s_setprio(1);
        #pragma unroll
        for (int nd = 0; nd < 4; ++nd) {
            const short8 bv0 = __builtin_shufflevector(v0l[nd], v0h[nd], 0, 1, 2, 3, 4, 5, 6, 7);
            o4[nd] = __builtin_amdgcn_mfma_f32_16x16x32_bf16(ap[0], bv0, o4[nd], 0, 0, 0);
            const short8 bv1 = __builtin_shufflevector(v1l[nd], v1h[nd], 0, 1, 2, 3, 4, 5, 6, 7);
            o4[nd] = __builtin_amdgcn_mfma_f32_16x16x32_bf16(ap[1], bv1, o4[nd], 0, 0, 0);
        }
        __builtin_amdgcn_s_setprio(0);
    }

    // ---- epilogue: pull lsum for q=lhi*4+r, normalize, write ----
    float inv[4];
    #pragma unroll
    for (int r = 0; r < 4; ++r) inv[r] = 1.f / __shfl(lsum, lhi * 4 + r, 64);
    #pragma unroll
    for (int nd = 0; nd < 4; ++nd) {
        const int d = nd * 16 + l15;
        #pragma unroll
        for (int r = 0; r < 4; ++r) {
            const int q = q0 + (wave << 4) + lhi * 4 + r;
            O[((size_t)(b * N_ + q)) * H_ + h * HD_ + d] = f2bf(o4[nd][r] * inv[r]);
        }
    }
}

// ---------------------------------------------------------------------------
extern "C" void kernel_launch(void* const* d_in, const int* in_sizes, int n_in,
                              void* d_out, int out_size, void* d_ws, size_t ws_size,
                              hipStream_t stream)
{
    const float* x    = (const float*)d_in[0];
    const float* dist = (const float*)d_in[1];
    const int*   mask = (const int*)d_in[2];
    const float* Wq   = (const float*)d_in[3];
    const float* bq   = (const float*)d_in[4];
    const float* Wk   = (const float*)d_in[5];
    const float* bk   = (const float*)d_in[6];
    const float* Wv   = (const float*)d_in[7];
    const float* bv   = (const float*)d_in[8];
    const float* Wo   = (const float*)d_in[9];
    const float* bo   = (const float*)d_in[10];
    const float* demb = (const float*)d_in[11];
    const float* ab   = (const float*)d_in[12];
    float* out = (float*)d_out;

    const size_t mat = (size_t)B_ * N_ * H_;         // 4,194,304
    const size_t wsz = (size_t)H_ * H_;              //   262,144

    unsigned short* blob = (unsigned short*)d_ws;
    unsigned short* xb  = blob;
    unsigned short* Wqb = blob + mat;
    unsigned short* Wkb = Wqb + wsz;
    unsigned short* Wvb = Wkb + wsz;
    unsigned short* Wob = Wvb + wsz;
    unsigned short* Qb  = Wob + wsz;
    unsigned short* Kb  = Qb + mat;
    unsigned short* Vb  = Kb + mat;
    unsigned short* Ab  = Vb + mat;
    unsigned char*  binsb = (unsigned char*)(Ab + mat);

    const dim3 blk(256);

    hipLaunchKernelGGL(cvt_all, dim3(1024), blk, 0, stream, x, Wq, Wk, Wv, Wo, blob);
    hipLaunchKernelGGL(bins_kernel, dim3((B_ * N_ * N_) / 16 / 256), blk, 0, stream,
                       dist, mask, binsb);

    const dim3 qgrid(H_ / 128, (B_ * N_) / 128, 3);
    hipLaunchKernelGGL(gemm_qkv, qgrid, blk, 0, stream,
                       xb, Wqb, Wkb, Wvb, bq, bk, bv, Qb, Kb, Vb);

    const dim3 agrid(N_ / 64, NH_, B_);
    hipLaunchKernelGGL(attn_mfma, agrid, blk, 0, stream,
                       Qb, Kb, Vb, binsb, demb, ab, Ab);

    const dim3 ogrid(H_ / 128, (B_ * N_) / 128, 1);
    hipLaunchKernelGGL(gemm_out, ogrid, blk, 0, stream, Ab, Wob, bo, out);
}